// Round 2
// baseline (327.703 us; speedup 1.0000x reference)
//
#include <hip/hip_runtime.h>
#include <hip/hip_bf16.h>
#include <stdint.h>

#define TT   2048
#define EMB  1024
#define SDIM 64
#define LOG2E 1.4426950408889634f

typedef float f32x4 __attribute__((ext_vector_type(4)));
typedef short short8 __attribute__((ext_vector_type(8)));
typedef unsigned short ushort4v __attribute__((ext_vector_type(4)));

__device__ __forceinline__ ushort f2bf(float f) {
    uint32_t u = __builtin_bit_cast(uint32_t, f);
    u += 0x7FFFu + ((u >> 16) & 1u);
    return (ushort)(u >> 16);
}

__device__ __forceinline__ short8 cvt8(const float* p) {
    f32x4 a = *(const f32x4*)p;
    f32x4 b = *(const f32x4*)(p + 4);
    short8 r;
    r[0] = (short)f2bf(a[0]); r[1] = (short)f2bf(a[1]);
    r[2] = (short)f2bf(a[2]); r[3] = (short)f2bf(a[3]);
    r[4] = (short)f2bf(b[0]); r[5] = (short)f2bf(b[1]);
    r[6] = (short)f2bf(b[2]); r[7] = (short)f2bf(b[3]);
    return r;
}

// ---------------- kernel 0: weight convert f32 -> bf16 ----------------
__global__ __launch_bounds__(256) void cvt_w(const float* __restrict__ Wk, const float* __restrict__ Wq,
                                             const float* __restrict__ Wv, const float* __restrict__ Wu,
                                             ushort* __restrict__ Wk16, ushort* __restrict__ Wq16,
                                             ushort* __restrict__ Wv16, ushort* __restrict__ Wu16) {
    int i = blockIdx.x * 256 + threadIdx.x;
    Wu16[i] = f2bf(Wu[i]);
    if (i < 4096) {
        Wk16[i] = f2bf(Wk[i]);
        Wq16[i] = f2bf(Wq[i] * (0.03125f * LOG2E));
        Wv16[i] = f2bf(Wv[i]);
    }
}

// ---------------- kernel 1: QKV projection (MFMA) ----------------
// Q,K stored (B,H,T,S) bf16; V stored TRANSPOSED (B,H,S,T) bf16.
__global__ __launch_bounds__(256) void qkv(const float* __restrict__ x,
                                           const ushort* __restrict__ Wk16, const ushort* __restrict__ Wq16,
                                           const ushort* __restrict__ Wv16,
                                           ushort* __restrict__ Qw, ushort* __restrict__ Kw, ushort* __restrict__ Vt) {
    const int tid = threadIdx.x;
    const int wave = tid >> 6, lane = tid & 63;
    const int c = lane & 15, g = lane >> 4;
    const int rblk = (blockIdx.x * 4 + wave) * 16;
    const int bh = rblk >> 11;
    const int tbase = rblk & (TT - 1);
    const int b = bh >> 4, h = bh & 15;

    const float* xrow = x + ((size_t)(b * TT + tbase + c) * EMB + h * SDIM);
    short8 a[2];
#pragma unroll
    for (int ks = 0; ks < 2; ++ks) a[ks] = cvt8(xrow + 32 * ks + 8 * g);

    f32x4 aq[4], ak[4], av[4];
#pragma unroll
    for (int n = 0; n < 4; ++n) { aq[n] = 0.f; ak[n] = 0.f; av[n] = 0.f; }

#pragma unroll
    for (int n = 0; n < 4; ++n) {
#pragma unroll
        for (int ks = 0; ks < 2; ++ks) {
            const size_t wo = (size_t)(16 * n + c) * SDIM + 32 * ks + 8 * g;
            short8 bq = *(const short8*)(Wq16 + wo);
            short8 bk = *(const short8*)(Wk16 + wo);
            short8 bv = *(const short8*)(Wv16 + wo);
            aq[n] = __builtin_amdgcn_mfma_f32_16x16x32_bf16(a[ks], bq, aq[n], 0, 0, 0);
            ak[n] = __builtin_amdgcn_mfma_f32_16x16x32_bf16(a[ks], bk, ak[n], 0, 0, 0);
            av[n] = __builtin_amdgcn_mfma_f32_16x16x32_bf16(a[ks], bv, av[n], 0, 0, 0);
        }
    }
    const size_t hb = (size_t)bh * TT * SDIM;
#pragma unroll
    for (int n = 0; n < 4; ++n) {
#pragma unroll
        for (int i = 0; i < 4; ++i) {
            const size_t o = hb + (size_t)(tbase + 4 * g + i) * SDIM + 16 * n + c;
            Qw[o] = f2bf(aq[n][i]);
            Kw[o] = f2bf(ak[n][i]);
        }
        // V transposed: Vt[bh][s=16n+c][t = tbase+4g+i] — 4 consecutive tokens pack to 8B
        ushort4v vp;
#pragma unroll
        for (int i = 0; i < 4; ++i) vp[i] = f2bf(av[n][i]);
        *(ushort4v*)(Vt + hb + (size_t)(16 * n + c) * TT + tbase + 4 * g) = vp;
    }
}

// ---------------- kernel 2: flash attention (barrier-free) ----------------
// grid (qtile=32, bh=32), 256 threads = 4 waves x 16 q-rows, KVBLK=64
// K,V fragments read directly from global (L2-served); only per-wave P tile in LDS.
__global__ __launch_bounds__(256) void attn(const ushort* __restrict__ Qw, const ushort* __restrict__ Kw,
                                            const ushort* __restrict__ Vt, ushort* __restrict__ AO) {
    __shared__ ushort Plds[4][16 * 64];    // per-wave P tile [q][kv], XOR-swizzled

    const int tid = threadIdx.x;
    const int wave = tid >> 6, lane = tid & 63;
    const int c = lane & 15, g = lane >> 4;
    const int bh = blockIdx.y;
    const int qrow = blockIdx.x * 64 + wave * 16;
    const size_t base = (size_t)bh * TT * SDIM;   // same for Qw/Kw (B,H,T,S) and Vt (B,H,S,T)

    short8 qa[2];
#pragma unroll
    for (int ks = 0; ks < 2; ++ks)
        qa[ks] = *(const short8*)(Qw + base + (size_t)(qrow + c) * SDIM + 32 * ks + 8 * g);

    f32x4 accO[4];
    float m_i[4], l_i[4];
#pragma unroll
    for (int n = 0; n < 4; ++n) accO[n] = 0.f;
#pragma unroll
    for (int i = 0; i < 4; ++i) { m_i[i] = -__builtin_inff(); l_i[i] = 0.f; }

    char* myP = (char*)&Plds[wave][0];

    for (int kt = 0; kt < 32; ++kt) {
        const int kvb = kt * 64;

        // S = Q·K^T ; B-frag = contiguous short8 from Kw row (kv = kvb+16n+c)
        f32x4 S[4];
#pragma unroll
        for (int n = 0; n < 4; ++n) S[n] = 0.f;
        const ushort* Kp = Kw + base + (size_t)(kvb + c) * SDIM + 8 * g;
#pragma unroll
        for (int n = 0; n < 4; ++n)
#pragma unroll
            for (int ks = 0; ks < 2; ++ks) {
                short8 bk = *(const short8*)(Kp + (size_t)(16 * n) * SDIM + 32 * ks);
                S[n] = __builtin_amdgcn_mfma_f32_16x16x32_bf16(qa[ks], bk, S[n], 0, 0, 0);
            }

        // online softmax (rows on 16-lane groups; logits already in exp2 domain)
        float mt[4];
#pragma unroll
        for (int i = 0; i < 4; ++i)
            mt[i] = fmaxf(fmaxf(S[0][i], S[1][i]), fmaxf(S[2][i], S[3][i]));
#pragma unroll
        for (int i = 0; i < 4; ++i) {
            mt[i] = fmaxf(mt[i], __shfl_xor(mt[i], 1));
            mt[i] = fmaxf(mt[i], __shfl_xor(mt[i], 2));
            mt[i] = fmaxf(mt[i], __shfl_xor(mt[i], 4));
            mt[i] = fmaxf(mt[i], __shfl_xor(mt[i], 8));
        }
        float al[4], rs[4];
#pragma unroll
        for (int i = 0; i < 4; ++i) {
            float mn = fmaxf(m_i[i], mt[i]);
            al[i] = __builtin_amdgcn_exp2f(m_i[i] - mn);
            m_i[i] = mn; rs[i] = 0.f;
        }
#pragma unroll
        for (int n = 0; n < 4; ++n)
#pragma unroll
            for (int i = 0; i < 4; ++i) {
                float p = __builtin_amdgcn_exp2f(S[n][i] - m_i[i]);
                S[n][i] = p; rs[i] += p;
            }
#pragma unroll
        for (int i = 0; i < 4; ++i) {
            rs[i] += __shfl_xor(rs[i], 1);
            rs[i] += __shfl_xor(rs[i], 2);
            rs[i] += __shfl_xor(rs[i], 4);
            rs[i] += __shfl_xor(rs[i], 8);
            l_i[i] = l_i[i] * al[i] + rs[i];
        }
#pragma unroll
        for (int n = 0; n < 4; ++n)
#pragma unroll
            for (int i = 0; i < 4; ++i) accO[n][i] *= al[i];

        // P -> per-wave LDS (wave-local: no barrier; compiler inserts lgkm waits)
#pragma unroll
        for (int n = 0; n < 4; ++n)
#pragma unroll
            for (int i = 0; i < 4; ++i) {
                int row = 4 * g + i;
                *(ushort*)(myP + row * 128 + (((16 * n + c) * 2) ^ ((row & 7) << 4))) = f2bf(S[n][i]);
            }

        // O += P·V ; A-frag = P from LDS, B-frag = contiguous short8 from Vt row (s = 16n+c)
        const ushort* Vp = Vt + base + (size_t)c * TT + kvb + 8 * g;
#pragma unroll
        for (int ks = 0; ks < 2; ++ks) {
            short8 pa = *(const short8*)(myP + c * 128 + ((64 * ks + 16 * g) ^ ((c & 7) << 4)));
#pragma unroll
            for (int n = 0; n < 4; ++n) {
                short8 bv = *(const short8*)(Vp + (size_t)(16 * n) * TT + 32 * ks);
                accO[n] = __builtin_amdgcn_mfma_f32_16x16x32_bf16(pa, bv, accO[n], 0, 0, 0);
            }
        }
    }

    // epilogue: normalize, store AO bf16 (B,T,EMB)
    const int b = bh >> 4, h = bh & 15;
    float inv[4];
#pragma unroll
    for (int i = 0; i < 4; ++i) inv[i] = 1.f / l_i[i];
#pragma unroll
    for (int n = 0; n < 4; ++n)
#pragma unroll
        for (int i = 0; i < 4; ++i) {
            size_t o = (size_t)(b * TT + qrow + 4 * g + i) * EMB + h * SDIM + 16 * n + c;
            AO[o] = f2bf(accO[n][i] * inv[i]);
        }
}

// ---------------- kernel 3: output projection + bias ----------------
__global__ __launch_bounds__(256) void oproj(const ushort* __restrict__ AO, const ushort* __restrict__ Wu16,
                                             const float* __restrict__ bu, float* __restrict__ out) {
    const int tid = threadIdx.x;
    const int wave = tid >> 6, lane = tid & 63;
    const int c = lane & 15, g = lane >> 4;
    const int rblk = blockIdx.x * 64 + wave * 16;
    const int ob = blockIdx.y * 64;

    f32x4 acc[4];
#pragma unroll
    for (int n = 0; n < 4; ++n) acc[n] = 0.f;

    for (int kt = 0; kt < 32; ++kt) {
        const int e0 = kt * 32;
        short8 a = *(const short8*)(AO + (size_t)(rblk + c) * EMB + e0 + 8 * g);
#pragma unroll
        for (int n = 0; n < 4; ++n) {
            short8 b = *(const short8*)(Wu16 + (size_t)(ob + 16 * n + c) * EMB + e0 + 8 * g);
            acc[n] = __builtin_amdgcn_mfma_f32_16x16x32_bf16(a, b, acc[n], 0, 0, 0);
        }
    }
#pragma unroll
    for (int n = 0; n < 4; ++n) {
        float bias = bu[ob + 16 * n + c];
#pragma unroll
        for (int i = 0; i < 4; ++i)
            out[(size_t)(rblk + 4 * g + i) * EMB + ob + 16 * n + c] = acc[n][i] + bias;
    }
}

extern "C" void kernel_launch(void* const* d_in, const int* in_sizes, int n_in,
                              void* d_out, int out_size, void* d_ws, size_t ws_size,
                              hipStream_t stream) {
    const float* x  = (const float*)d_in[0];
    const float* Wk = (const float*)d_in[1];
    const float* Wq = (const float*)d_in[2];
    const float* Wv = (const float*)d_in[3];
    const float* Wu = (const float*)d_in[4];
    const float* bu = (const float*)d_in[5];
    float* out = (float*)d_out;

    char* ws = (char*)d_ws;
    const size_t MB = 1024u * 1024u;
    ushort* Qw   = (ushort*)(ws);             // 8 MB  (B,H,T,S) bf16
    ushort* Kw   = (ushort*)(ws + 8 * MB);    // 8 MB  (B,H,T,S) bf16
    ushort* Vt   = (ushort*)(ws + 16 * MB);   // 8 MB  (B,H,S,T) bf16  (transposed V)
    ushort* AO   = (ushort*)(ws + 24 * MB);   // 8 MB  (B,T,EMB) bf16
    ushort* Wu16 = (ushort*)(ws + 32 * MB);   // 2 MB
    ushort* Wk16 = (ushort*)(ws + 34 * MB);   // 8 KB x3
    ushort* Wq16 = Wk16 + 4096;
    ushort* Wv16 = Wk16 + 8192;

    cvt_w<<<dim3(4096), dim3(256), 0, stream>>>(Wk, Wq, Wv, Wu, Wk16, Wq16, Wv16, Wu16);
    qkv<<<dim3(1024), dim3(256), 0, stream>>>(x, Wk16, Wq16, Wv16, Qw, Kw, Vt);
    attn<<<dim3(32, 32), dim3(256), 0, stream>>>(Qw, Kw, Vt, AO);
    oproj<<<dim3(64, 16), dim3(256), 0, stream>>>(AO, Wu16, bu, out);
}

// Round 3
// 93.944 us; speedup vs baseline: 3.4883x; 3.4883x over previous
//
#include <hip/hip_runtime.h>
#include <hip/hip_bf16.h>
#include <stdint.h>

#define TT   2048
#define EMB  1024
#define SDIM 64
#define LOG2E 1.4426950408889634f

typedef float f32x4  __attribute__((ext_vector_type(4)));
typedef float f32x16 __attribute__((ext_vector_type(16)));
typedef short short8 __attribute__((ext_vector_type(8)));
typedef unsigned short ushort4v __attribute__((ext_vector_type(4)));
typedef unsigned int uint2v __attribute__((ext_vector_type(2)));
typedef unsigned int uint4v __attribute__((ext_vector_type(4)));

__device__ __forceinline__ ushort f2bf(float f) {
    uint32_t u = __builtin_bit_cast(uint32_t, f);
    u += 0x7FFFu + ((u >> 16) & 1u);
    return (ushort)(u >> 16);
}

__device__ __forceinline__ short8 cvt8(const float* p) {
    f32x4 a = *(const f32x4*)p;
    f32x4 b = *(const f32x4*)(p + 4);
    short8 r;
    r[0] = (short)f2bf(a[0]); r[1] = (short)f2bf(a[1]);
    r[2] = (short)f2bf(a[2]); r[3] = (short)f2bf(a[3]);
    r[4] = (short)f2bf(b[0]); r[5] = (short)f2bf(b[1]);
    r[6] = (short)f2bf(b[2]); r[7] = (short)f2bf(b[3]);
    return r;
}

// async global->LDS, 16B per lane; lds dst must be wave-uniform base (HW adds lane*16)
__device__ __forceinline__ void gload16(const void* g, void* l) {
    __builtin_amdgcn_global_load_lds((const __attribute__((address_space(1))) uint32_t*)g,
                                     (__attribute__((address_space(3))) uint32_t*)l, 16, 0, 0);
}
// pack two f32 -> dword of 2 bf16 (lo=a, hi=b)
__device__ __forceinline__ uint pkbf(float a, float b) {
    uint d; asm("v_cvt_pk_bf16_f32 %0, %1, %2" : "=v"(d) : "v"(a), "v"(b)); return d;
}
// exchange a's high 32 lanes with b's low 32 lanes
__device__ __forceinline__ void swap32(uint& a, uint& b) {
    asm volatile("v_permlane32_swap_b32 %0, %1" : "+v"(a), "+v"(b));
}

// ---------------- kernel 0: weight convert f32 -> bf16 ----------------
__global__ __launch_bounds__(256) void cvt_w(const float* __restrict__ Wk, const float* __restrict__ Wq,
                                             const float* __restrict__ Wv, const float* __restrict__ Wu,
                                             ushort* __restrict__ Wk16, ushort* __restrict__ Wq16,
                                             ushort* __restrict__ Wv16, ushort* __restrict__ Wu16) {
    int i = blockIdx.x * 256 + threadIdx.x;
    Wu16[i] = f2bf(Wu[i]);
    if (i < 4096) {
        Wk16[i] = f2bf(Wk[i]);
        Wq16[i] = f2bf(Wq[i] * (0.03125f * LOG2E));   // scale^2 * log2(e) folded
        Wv16[i] = f2bf(Wv[i]);
    }
}

// ---------------- kernel 1: QKV projection (MFMA) ----------------
// Q,K stored (B,H,T,S) bf16; V stored TRANSPOSED (B,H,S,T) bf16.
__global__ __launch_bounds__(256) void qkv(const float* __restrict__ x,
                                           const ushort* __restrict__ Wk16, const ushort* __restrict__ Wq16,
                                           const ushort* __restrict__ Wv16,
                                           ushort* __restrict__ Qw, ushort* __restrict__ Kw, ushort* __restrict__ Vt) {
    const int tid = threadIdx.x;
    const int wave = tid >> 6, lane = tid & 63;
    const int c = lane & 15, g = lane >> 4;
    const int rblk = (blockIdx.x * 4 + wave) * 16;
    const int bh = rblk >> 11;
    const int tbase = rblk & (TT - 1);
    const int b = bh >> 4, h = bh & 15;

    const float* xrow = x + ((size_t)(b * TT + tbase + c) * EMB + h * SDIM);
    short8 a[2];
#pragma unroll
    for (int ks = 0; ks < 2; ++ks) a[ks] = cvt8(xrow + 32 * ks + 8 * g);

    f32x4 aq[4], ak[4], av[4];
#pragma unroll
    for (int n = 0; n < 4; ++n) { aq[n] = 0.f; ak[n] = 0.f; av[n] = 0.f; }

#pragma unroll
    for (int n = 0; n < 4; ++n) {
#pragma unroll
        for (int ks = 0; ks < 2; ++ks) {
            const size_t wo = (size_t)(16 * n + c) * SDIM + 32 * ks + 8 * g;
            short8 bq = *(const short8*)(Wq16 + wo);
            short8 bk = *(const short8*)(Wk16 + wo);
            short8 bv = *(const short8*)(Wv16 + wo);
            aq[n] = __builtin_amdgcn_mfma_f32_16x16x32_bf16(a[ks], bq, aq[n], 0, 0, 0);
            ak[n] = __builtin_amdgcn_mfma_f32_16x16x32_bf16(a[ks], bk, ak[n], 0, 0, 0);
            av[n] = __builtin_amdgcn_mfma_f32_16x16x32_bf16(a[ks], bv, av[n], 0, 0, 0);
        }
    }
    const size_t hb = (size_t)bh * TT * SDIM;
#pragma unroll
    for (int n = 0; n < 4; ++n) {
#pragma unroll
        for (int i = 0; i < 4; ++i) {
            const size_t o = hb + (size_t)(tbase + 4 * g + i) * SDIM + 16 * n + c;
            Qw[o] = f2bf(aq[n][i]);
            Kw[o] = f2bf(ak[n][i]);
        }
        ushort4v vp;
#pragma unroll
        for (int i = 0; i < 4; ++i) vp[i] = f2bf(av[n][i]);
        *(ushort4v*)(Vt + hb + (size_t)(16 * n + c) * TT + tbase + 4 * g) = vp;
    }
}

// ---------------- kernel 2: flash attention, 8-wave 32x32 swapped-QK^T ----------------
// flat grid 256; xcd-aware: each XCD owns 4 heads (K/V L2-resident).
// per wave: 32 q-rows in regs; per block KVBLK=64 staged dbuf in LDS via global_load_lds.
__global__ __launch_bounds__(512) void attn(const ushort* __restrict__ Qw, const ushort* __restrict__ Kw,
                                            const ushort* __restrict__ Vt, ushort* __restrict__ AO) {
    __shared__ ushort smem[4][4096];   // [0,1]=K dbuf, [2,3]=V dbuf; reused as epilogue scratch

    const int tid = threadIdx.x;
    const int wv = tid >> 6, lane = tid & 63;
    const int q = lane & 31, hi = lane >> 5;

    const int wg = blockIdx.x;            // 0..255
    const int xcd = wg & 7, slot = wg >> 3;
    const int bh = xcd * 4 + (slot >> 3); // 4 heads per XCD
    const int qt = slot & 7;
    const int b = bh >> 4, h = bh & 15;
    const int qrowW = qt * 256 + wv * 32;
    const size_t base = (size_t)bh * TT * SDIM;

    // Q B-frags: qa[sb][i] = Q[q][16*sb + 8*hi + i]
    short8 qa[4];
    const ushort* Qp = Qw + base + (size_t)(qrowW + q) * SDIM + 8 * hi;
#pragma unroll
    for (int sb = 0; sb < 4; ++sb) qa[sb] = *(const short8*)(Qp + 16 * sb);

    f32x16 a0v = 0.f, a1v = 0.f;         // O^T accum: s-blocks 0..31 / 32..63
    float m_i = -__builtin_inff(), l_i = 0.f;

    // staging map: thread -> (row = tid>>3, swizzled col), LDS linear slot tid*16B
    const int srow = tid >> 3;
    const int scol = ((tid & 7) ^ (srow & 7)) * 8;
    const ushort* Ksrc = Kw + base + (size_t)srow * SDIM + scol;
    const ushort* Vsrc = Vt + base + (size_t)srow * TT + scol;
    const int ldst = wv * 512;           // ushort offset of wave's 1KB staging slice

    gload16(Ksrc, &smem[0][ldst]);
    gload16(Vsrc, &smem[2][ldst]);
    __syncthreads();

    const int kswz = (q & 7) << 4;
    int cur = 0;
    for (int kt = 0; kt < 32; ++kt) {
        if (kt < 31) {   // prefetch next tile into other buffer
            gload16(Ksrc + (size_t)(kt + 1) * 64 * SDIM, &smem[cur ^ 1][ldst]);
            gload16(Vsrc + (size_t)(kt + 1) * 64,        &smem[2 + (cur ^ 1)][ldst]);
        }
        const char* Kc = (const char*)&smem[cur][0];
        const char* Vc = (const char*)&smem[2 + cur][0];

        // S^T = K · Q^T  (two 32-row kv blocks)
        f32x16 s0v = 0.f, s1v = 0.f;
#pragma unroll
        for (int sb = 0; sb < 4; ++sb) {
            short8 k0 = *(const short8*)(Kc + q * 128 + ((32 * sb + 16 * hi) ^ kswz));
            s0v = __builtin_amdgcn_mfma_f32_32x32x16_bf16(k0, qa[sb], s0v, 0, 0, 0);
            short8 k1 = *(const short8*)(Kc + (32 + q) * 128 + ((32 * sb + 16 * hi) ^ kswz));
            s1v = __builtin_amdgcn_mfma_f32_32x32x16_bf16(k1, qa[sb], s1v, 0, 0, 0);
        }

        // softmax: lane owns row q; 32 local values + cross-half swap
        float pm = s0v[0];
#pragma unroll
        for (int i = 1; i < 16; ++i) pm = fmaxf(pm, s0v[i]);
#pragma unroll
        for (int i = 0; i < 16; ++i) pm = fmaxf(pm, s1v[i]);
        pm = fmaxf(pm, __shfl_xor(pm, 32));
        float mnew = fmaxf(m_i, pm);
        float al = __builtin_amdgcn_exp2f(m_i - mnew);
        m_i = mnew;
        float rs = 0.f;
#pragma unroll
        for (int i = 0; i < 16; ++i) { float p = __builtin_amdgcn_exp2f(s0v[i] - mnew); s0v[i] = p; rs += p; }
#pragma unroll
        for (int i = 0; i < 16; ++i) { float p = __builtin_amdgcn_exp2f(s1v[i] - mnew); s1v[i] = p; rs += p; }
        rs += __shfl_xor(rs, 32);
        l_i = l_i * al + rs;
#pragma unroll
        for (int i = 0; i < 16; ++i) { a0v[i] *= al; a1v[i] *= al; }

        // repack P^T (D-layout: kv=(r&3)+8*(r>>2)+4*hi) -> PV B-frags (k=8*hi+i)
        short8 pb0, pb1, pb2, pb3;
        {
            uint u0 = pkbf(s0v[0], s0v[1]),   u1 = pkbf(s0v[2], s0v[3]);
            uint u2 = pkbf(s0v[4], s0v[5]),   u3 = pkbf(s0v[6], s0v[7]);
            swap32(u0, u2); swap32(u1, u3);
            uint4v t0 = {u0, u1, u2, u3}; pb0 = __builtin_bit_cast(short8, t0);
            uint u4 = pkbf(s0v[8], s0v[9]),   u5 = pkbf(s0v[10], s0v[11]);
            uint u6 = pkbf(s0v[12], s0v[13]), u7 = pkbf(s0v[14], s0v[15]);
            swap32(u4, u6); swap32(u5, u7);
            uint4v t1 = {u4, u5, u6, u7}; pb1 = __builtin_bit_cast(short8, t1);
            uint w0 = pkbf(s1v[0], s1v[1]),   w1 = pkbf(s1v[2], s1v[3]);
            uint w2 = pkbf(s1v[4], s1v[5]),   w3 = pkbf(s1v[6], s1v[7]);
            swap32(w0, w2); swap32(w1, w3);
            uint4v t2 = {w0, w1, w2, w3}; pb2 = __builtin_bit_cast(short8, t2);
            uint w4 = pkbf(s1v[8], s1v[9]),   w5 = pkbf(s1v[10], s1v[11]);
            uint w6 = pkbf(s1v[12], s1v[13]), w7 = pkbf(s1v[14], s1v[15]);
            swap32(w4, w6); swap32(w5, w7);
            uint4v t3 = {w4, w5, w6, w7}; pb3 = __builtin_bit_cast(short8, t3);
        }

        // O^T += V^T · P^T   (A = Vt rows, kv is the contraction dim)
#pragma unroll
        for (int kstep = 0; kstep < 4; ++kstep) {
            short8 pbk = (kstep == 0) ? pb0 : (kstep == 1) ? pb1 : (kstep == 2) ? pb2 : pb3;
            short8 v0 = *(const short8*)(Vc + q * 128 + ((32 * kstep + 16 * hi) ^ kswz));
            a0v = __builtin_amdgcn_mfma_f32_32x32x16_bf16(v0, pbk, a0v, 0, 0, 0);
            short8 v1 = *(const short8*)(Vc + (32 + q) * 128 + ((32 * kstep + 16 * hi) ^ kswz));
            a1v = __builtin_amdgcn_mfma_f32_32x32x16_bf16(v1, pbk, a1v, 0, 0, 0);
        }
        __syncthreads();
        cur ^= 1;
    }

    // epilogue: per-wave LDS transpose (reuse staging buffers), coalesced AO store
    char* scrB = (char*)(&smem[0][0] + wv * 2048);   // 32 rows x 128B
    float inv = 1.f / l_i;
#pragma unroll
    for (int sb2 = 0; sb2 < 2; ++sb2) {
#pragma unroll
        for (int bq = 0; bq < 4; ++bq) {
            float v0 = (sb2 ? a1v[4 * bq + 0] : a0v[4 * bq + 0]) * inv;
            float v1 = (sb2 ? a1v[4 * bq + 1] : a0v[4 * bq + 1]) * inv;
            float v2 = (sb2 ? a1v[4 * bq + 2] : a0v[4 * bq + 2]) * inv;
            float v3 = (sb2 ? a1v[4 * bq + 3] : a0v[4 * bq + 3]) * inv;
            uint2v d; d[0] = pkbf(v0, v1); d[1] = pkbf(v2, v3);
            int s0 = 8 * bq + 4 * hi + 32 * sb2;
            *(uint2v*)(scrB + q * 128 + ((s0 * 2) ^ kswz)) = d;
        }
    }
    asm volatile("s_waitcnt lgkmcnt(0)" ::: "memory");
    ushort* AOp = AO + (size_t)(b * TT + qrowW + q) * EMB + h * SDIM + 32 * hi;
#pragma unroll
    for (int jj = 0; jj < 4; ++jj) {
        short8 o = *(const short8*)(scrB + q * 128 + ((64 * hi + 16 * jj) ^ kswz));
        *(short8*)(AOp + 8 * jj) = o;
    }
}

// ---------------- kernel 3: output projection, 128x128 tile, LDS dbuf ----------------
__global__ __launch_bounds__(512) void oproj(const ushort* __restrict__ AO, const ushort* __restrict__ Wu16,
                                             const float* __restrict__ bu, float* __restrict__ out) {
    __shared__ ushort Ab[2][128 * 64];
    __shared__ ushort Bb[2][128 * 64];
    const int tid = threadIdx.x;
    const int wv = tid >> 6, lane = tid & 63;
    const int c = lane & 15, g = lane >> 4;
    const int wr = wv >> 1, wc = wv & 1;        // 4x2 wave grid: wave tile 32x64
    const int rblk = blockIdx.x * 128, nblk = blockIdx.y * 128;

    const int row0 = tid >> 3;
    const int col0 = ((tid & 7) ^ (row0 & 7)) * 8;   // (row0+64)&7 == row0&7, so pass1 col same
    const ushort* As0 = AO   + (size_t)(rblk + row0) * EMB + col0;
    const ushort* As1 = AO   + (size_t)(rblk + row0 + 64) * EMB + col0;
    const ushort* Bs0 = Wu16 + (size_t)(nblk + row0) * EMB + col0;
    const ushort* Bs1 = Wu16 + (size_t)(nblk + row0 + 64) * EMB + col0;
    const int l0 = wv * 512, l1 = 4096 + wv * 512;

    f32x4 acc[2][4];
#pragma unroll
    for (int m = 0; m < 2; ++m)
#pragma unroll
        for (int n = 0; n < 4; ++n) acc[m][n] = 0.f;

    gload16(As0, &Ab[0][l0]); gload16(As1, &Ab[0][l1]);
    gload16(Bs0, &Bb[0][l0]); gload16(Bs1, &Bb[0][l1]);
    __syncthreads();

    const int swzA = (c & 7) << 4;
    int cur = 0;
    for (int kt = 0; kt < 16; ++kt) {
        if (kt < 15) {
            const int k0 = (kt + 1) * 64;
            gload16(As0 + k0, &Ab[cur ^ 1][l0]); gload16(As1 + k0, &Ab[cur ^ 1][l1]);
            gload16(Bs0 + k0, &Bb[cur ^ 1][l0]); gload16(Bs1 + k0, &Bb[cur ^ 1][l1]);
        }
        const char* Ac = (const char*)&Ab[cur][0];
        const char* Bc = (const char*)&Bb[cur][0];
#pragma unroll
        for (int kb = 0; kb < 2; ++kb) {
            short8 am[2], bn[4];
#pragma unroll
            for (int m = 0; m < 2; ++m)
                am[m] = *(const short8*)(Ac + (wr * 32 + 16 * m + c) * 128 + ((64 * kb + 16 * g) ^ swzA));
#pragma unroll
            for (int n = 0; n < 4; ++n)
                bn[n] = *(const short8*)(Bc + (wc * 64 + 16 * n + c) * 128 + ((64 * kb + 16 * g) ^ swzA));
#pragma unroll
            for (int m = 0; m < 2; ++m)
#pragma unroll
                for (int n = 0; n < 4; ++n)
                    acc[m][n] = __builtin_amdgcn_mfma_f32_16x16x32_bf16(am[m], bn[n], acc[m][n], 0, 0, 0);
        }
        __syncthreads();
        cur ^= 1;
    }
#pragma unroll
    for (int m = 0; m < 2; ++m)
#pragma unroll
        for (int n = 0; n < 4; ++n) {
            float bias = bu[nblk + wc * 64 + 16 * n + c];
#pragma unroll
            for (int i = 0; i < 4; ++i)
                out[(size_t)(rblk + wr * 32 + 16 * m + 4 * g + i) * EMB + nblk + wc * 64 + 16 * n + c] =
                    acc[m][n][i] + bias;
        }
}

extern "C" void kernel_launch(void* const* d_in, const int* in_sizes, int n_in,
                              void* d_out, int out_size, void* d_ws, size_t ws_size,
                              hipStream_t stream) {
    const float* x  = (const float*)d_in[0];
    const float* Wk = (const float*)d_in[1];
    const float* Wq = (const float*)d_in[2];
    const float* Wv = (const float*)d_in[3];
    const float* Wu = (const float*)d_in[4];
    const float* bu = (const float*)d_in[5];
    float* out = (float*)d_out;

    char* ws = (char*)d_ws;
    const size_t MB = 1024u * 1024u;
    ushort* Qw   = (ushort*)(ws);             // 8 MB  (B,H,T,S) bf16
    ushort* Kw   = (ushort*)(ws + 8 * MB);    // 8 MB  (B,H,T,S) bf16
    ushort* Vt   = (ushort*)(ws + 16 * MB);   // 8 MB  (B,H,S,T) bf16
    ushort* AO   = (ushort*)(ws + 24 * MB);   // 8 MB  (B,T,EMB) bf16
    ushort* Wu16 = (ushort*)(ws + 32 * MB);   // 2 MB
    ushort* Wk16 = (ushort*)(ws + 34 * MB);   // 8 KB x3
    ushort* Wq16 = Wk16 + 4096;
    ushort* Wv16 = Wk16 + 8192;

    cvt_w<<<dim3(4096), dim3(256), 0, stream>>>(Wk, Wq, Wv, Wu, Wk16, Wq16, Wv16, Wu16);
    qkv<<<dim3(1024), dim3(256), 0, stream>>>(x, Wk16, Wq16, Wv16, Qw, Kw, Vt);
    attn<<<dim3(256), dim3(512), 0, stream>>>(Qw, Kw, Vt, AO);
    oproj<<<dim3(32, 8), dim3(512), 0, stream>>>(AO, Wu16, bu, out);
}